// Round 2
// baseline (81.584 us; speedup 1.0000x reference)
//
#include <hip/hip_runtime.h>
#include <hip/hip_bf16.h>

#define N_TOK 2048
#define HQ_ 16
#define HKV_ 4
#define D_ 128
#define NUM_SLOTS_ 131072
#define SEQ_ 512
#define NSEG_ 4

typedef __attribute__((ext_vector_type(8))) short bf16x8;
typedef __attribute__((ext_vector_type(4))) float f32x4;
typedef __attribute__((ext_vector_type(4))) short s16x4;

__device__ __forceinline__ short f2bf(float x) {
  union { float f; unsigned u; } un; un.f = x;
  unsigned r = un.u + 0x7FFFu + ((un.u >> 16) & 1u);
  return (short)(r >> 16);
}

// Fused prep:
//  blocks [0,1024): k_bf [N][HKV][D] bf16, vectorized f32x4 -> short4 (coalesced both sides)
//  blocks [1024,1152): vt [NSEG][HKV][D][SEQ] bf16, d-major so token-dim writes coalesce
__global__ __launch_bounds__(256) void prep_kernel(
    const float* __restrict__ k, const float* __restrict__ v,
    const float* __restrict__ k_cache, const float* __restrict__ v_cache,
    const int* __restrict__ slot_mapping,
    short* __restrict__ k_bf, short* __restrict__ vt) {
  int b = blockIdx.x;
  if (b < 1024) {
    int idx = (b * 256 + (int)threadIdx.x) * 4;  // N*HKV*D = 1048576 = 1024*256*4 exact
    int n = idx >> 9;
    int s = slot_mapping[n];
    bool valid = (s >= 0) && (s < NUM_SLOTS_);
    int cs = s < 0 ? 0 : (s >= NUM_SLOTS_ ? NUM_SLOTS_ - 1 : s);
    const float* src = valid ? (k + idx)
                             : (k_cache + (size_t)cs * (HKV_ * D_) + (idx & (HKV_ * D_ - 1)));
    f32x4 a = *(const f32x4*)src;
    s16x4 o;
#pragma unroll
    for (int j = 0; j < 4; ++j) o[j] = f2bf(a[j]);
    *(s16x4*)(k_bf + idx) = o;
  } else {
    int bb = b - 1024;                  // 128 blocks: [seg][h][dblk of 16]
    int dblk = bb & 7, h = (bb >> 3) & 3, seg = bb >> 5;
    int d0 = dblk * 16;
#pragma unroll
    for (int tp = 0; tp < 2; ++tp) {
      int tok = tp * 256 + (int)threadIdx.x;
      int n = seg * SEQ_ + tok;
      int s = slot_mapping[n];
      bool valid = (s >= 0) && (s < NUM_SLOTS_);
      int cs = s < 0 ? 0 : (s >= NUM_SLOTS_ ? NUM_SLOTS_ - 1 : s);
      const float* src = valid ? (v + (size_t)n * (HKV_ * D_) + h * D_ + d0)
                               : (v_cache + (size_t)cs * (HKV_ * D_) + h * D_ + d0);
      short* dst = vt + ((size_t)((seg * HKV_ + h) * D_ + d0)) * SEQ_ + tok;
      f32x4 x0 = *(const f32x4*)(src + 0);
      f32x4 x1 = *(const f32x4*)(src + 4);
      f32x4 x2 = *(const f32x4*)(src + 8);
      f32x4 x3 = *(const f32x4*)(src + 12);
#pragma unroll
      for (int j = 0; j < 4; ++j) {
        dst[(size_t)(0 + j) * SEQ_] = f2bf(x0[j]);
        dst[(size_t)(4 + j) * SEQ_] = f2bf(x1[j]);
        dst[(size_t)(8 + j) * SEQ_] = f2bf(x2[j]);
        dst[(size_t)(12 + j) * SEQ_] = f2bf(x3[j]);
      }
    }
  }
}

// 2 waves per block, same 16-row q-tile, split-K over 32-key blocks (alternating),
// merged at the end via LDS. No barriers / LDS in the main loop: P^T redistribution
// is done in-register with 8 shfl + uniform selects.
// S^T = mfma(K, Q): C/D col = lane&15 = q, row = grp*4+reg = key.
// O^T = mfma(V^T, P^T): col = q, row = d.
__global__ __launch_bounds__(128) void attn_kernel(
    const float* __restrict__ q, const short* __restrict__ k_bf,
    const short* __restrict__ vt, float* __restrict__ out) {
  __shared__ float sm_o[32 * 64];   // [d-frag j=t*4+r][lane]
  __shared__ float sm_ml[128];
  const int tid = (int)threadIdx.x;
  const int wave = tid >> 6;
  const int lane = tid & 63;
  const int col = lane & 15;        // q column
  const int grp = lane >> 4;        // 0..3
  const int bid = blockIdx.x;
  const int qtile = bid & 31;
  const int head = (bid >> 5) & 15;
  const int seg = bid >> 9;
  const int kvh = head >> 2;
  const int q0 = qtile << 4;

  // Q fragments (B-operand): lane holds q=col, k-dim d = t*32 + grp*8 + j. Scale folded in.
  bf16x8 qf[4];
  {
    const float* qp = q + ((size_t)((seg * SEQ_ + q0 + col) * HQ_ + head)) * D_ + grp * 8;
    const float sc = 0.08838834764831843f;  // 1/sqrt(128)
#pragma unroll
    for (int t = 0; t < 4; ++t) {
      f32x4 a = *(const f32x4*)(qp + t * 32);
      f32x4 bvec = *(const f32x4*)(qp + t * 32 + 4);
      bf16x8 f;
#pragma unroll
      for (int j = 0; j < 4; ++j) { f[j] = f2bf(a[j] * sc); f[4 + j] = f2bf(bvec[j] * sc); }
      qf[t] = f;
    }
  }

  f32x4 o_acc[8];
#pragma unroll
  for (int t = 0; t < 8; ++t) o_acc[t] = (f32x4){0.f, 0.f, 0.f, 0.f};
  float m = -1e30f, l_sum = 0.f;
  const int qpos = q0 + col;
  const int nb = (q0 + 47) >> 5;    // ceil((q0+16)/32) 32-key blocks
  const float c = 1.44269504f;

  const short* kseg = k_bf + (size_t)(seg * SEQ_ * HKV_ + kvh) * D_ + col * (HKV_ * D_) + grp * 8;
  const short* vseg = vt + ((size_t)((seg * HKV_ + kvh) * D_ + col)) * SEQ_ + grp * 8;
  const int srcA = col + ((grp & 1) << 5);  // exchange partners (same col)
  const int srcB = srcA + 16;

  for (int blk = wave; blk < nb; blk += 2) {
    const int k0 = blk << 5;
    // ---- S^T = K · Q^T over D=128 (keys k0..k0+31) ----
    f32x4 s0 = {0.f, 0.f, 0.f, 0.f}, s1 = {0.f, 0.f, 0.f, 0.f};
    const short* kp = kseg + (size_t)k0 * (HKV_ * D_);
#pragma unroll
    for (int t = 0; t < 4; ++t) {
      bf16x8 kf = *(const bf16x8*)(kp + t * 32);
      s0 = __builtin_amdgcn_mfma_f32_16x16x32_bf16(kf, qf[t], s0, 0, 0, 0);
    }
#pragma unroll
    for (int t = 0; t < 4; ++t) {
      bf16x8 kf = *(const bf16x8*)(kp + 16 * (HKV_ * D_) + t * 32);
      s1 = __builtin_amdgcn_mfma_f32_16x16x32_bf16(kf, qf[t], s1, 0, 0, 0);
    }

    // ---- causal mask + online softmax ----
    float vmax = -1e30f;
#pragma unroll
    for (int r = 0; r < 4; ++r) {
      int kk = k0 + grp * 4 + r;
      if (kk > qpos) s0[r] = -1e30f;
      if (kk + 16 > qpos) s1[r] = -1e30f;
      vmax = fmaxf(vmax, fmaxf(s0[r], s1[r]));
    }
    vmax = fmaxf(vmax, __shfl_xor(vmax, 16));
    vmax = fmaxf(vmax, __shfl_xor(vmax, 32));
    const float m_new = fmaxf(m, vmax);
    const float alpha = exp2f((m - m_new) * c);
    float rsum = 0.f;
#pragma unroll
    for (int r = 0; r < 4; ++r) {
      s0[r] = exp2f((s0[r] - m_new) * c);
      s1[r] = exp2f((s1[r] - m_new) * c);
      rsum += s0[r] + s1[r];
    }
    rsum += __shfl_xor(rsum, 16);
    rsum += __shfl_xor(rsum, 32);
    m = m_new;
    l_sum = l_sum * alpha + rsum;
#pragma unroll
    for (int t = 0; t < 8; ++t) o_acc[t] *= alpha;

    // ---- P^T -> PV B-fragment, fully in-register ----
    // lane holds keys grp*4+r (s0) and 16+grp*4+r (s1); B-frag needs keys grp*8+j.
    unsigned u0 = ((unsigned)(unsigned short)f2bf(s0[1]) << 16) | (unsigned short)f2bf(s0[0]);
    unsigned u1 = ((unsigned)(unsigned short)f2bf(s0[3]) << 16) | (unsigned short)f2bf(s0[2]);
    unsigned u2 = ((unsigned)(unsigned short)f2bf(s1[1]) << 16) | (unsigned short)f2bf(s1[0]);
    unsigned u3 = ((unsigned)(unsigned short)f2bf(s1[3]) << 16) | (unsigned short)f2bf(s1[2]);
    int a0 = __shfl((int)u0, srcA, 64), a1 = __shfl((int)u1, srcA, 64);
    int a2 = __shfl((int)u2, srcA, 64), a3 = __shfl((int)u3, srcA, 64);
    int b0 = __shfl((int)u0, srcB, 64), b1 = __shfl((int)u1, srcB, 64);
    int b2 = __shfl((int)u2, srcB, 64), b3 = __shfl((int)u3, srcB, 64);
    union { bf16x8 v; int u[4]; } pf;
    const bool lo2 = grp < 2;
    pf.u[0] = lo2 ? a0 : a2;
    pf.u[1] = lo2 ? a1 : a3;
    pf.u[2] = lo2 ? b0 : b2;
    pf.u[3] = lo2 ? b1 : b3;

    // ---- O^T += V^T · P^T ----
    const short* vp = vseg + k0;
#pragma unroll
    for (int t = 0; t < 8; ++t) {
      bf16x8 vf = *(const bf16x8*)(vp + (size_t)(t * 16) * SEQ_);
      o_acc[t] = __builtin_amdgcn_mfma_f32_16x16x32_bf16(vf, pf.v, o_acc[t], 0, 0, 0);
    }
  }

  // ---- split-K merge (wave1 -> LDS, wave0 merges + writes) ----
  if (wave) {
    sm_ml[lane] = m;
    sm_ml[64 + lane] = l_sum;
#pragma unroll
    for (int t = 0; t < 8; ++t)
#pragma unroll
      for (int r = 0; r < 4; ++r) sm_o[(t * 4 + r) * 64 + lane] = o_acc[t][r];
  }
  __syncthreads();
  if (!wave) {
    float m1 = sm_ml[lane], l1 = sm_ml[64 + lane];
    float mx = fmaxf(m, m1);
    float a0 = exp2f((m - mx) * c);
    float a1 = exp2f((m1 - mx) * c);
    float linv = 1.0f / (l_sum * a0 + l1 * a1);
    float* op = out + ((size_t)((seg * SEQ_ + q0 + col) * HQ_ + head)) * D_ + grp * 4;
#pragma unroll
    for (int t = 0; t < 8; ++t) {
      f32x4 r;
#pragma unroll
      for (int j = 0; j < 4; ++j)
        r[j] = (o_acc[t][j] * a0 + sm_o[(t * 4 + j) * 64 + lane] * a1) * linv;
      *(f32x4*)(op + t * 16) = r;
    }
  }
}

extern "C" void kernel_launch(void* const* d_in, const int* in_sizes, int n_in,
                              void* d_out, int out_size, void* d_ws, size_t ws_size,
                              hipStream_t stream) {
  const float* q = (const float*)d_in[0];
  const float* k = (const float*)d_in[1];
  const float* v = (const float*)d_in[2];
  const float* k_cache = (const float*)d_in[3];
  const float* v_cache = (const float*)d_in[4];
  const int* slot_mapping = (const int*)d_in[5];

  short* k_bf = (short*)d_ws;                               // 2 MB
  short* vt = k_bf + (size_t)N_TOK * HKV_ * D_;             // 2 MB

  prep_kernel<<<1152, 256, 0, stream>>>(k, v, k_cache, v_cache, slot_mapping, k_bf, vt);
  attn_kernel<<<NSEG_ * HQ_ * 32, 128, 0, stream>>>(q, k_bf, vt, (float*)d_out);
}